// Round 3
// baseline (585.513 us; speedup 1.0000x reference)
//
#include <hip/hip_runtime.h>

// Problem constants (must match reference)
#define NUM_PHYSICAL 2000000
#define NUM_NODES    2500000   // 2,000,000 physical + 500,000 filler
#define NBX 512
#define NBY 512
#define NBINS (NBX * NBY)
#define NXCD 8

// BSX = BSY = 1000/512 = 1.953125 (exact in binary)
#define BSX 1.953125f
#define BSY 1.953125f
#define HALF_STRETCH ((float)(0.5 * 1.953125 * 1.4142135623730951))
// BSX*BSY*UNIT_PIN_CAPACITY = 61.03515625 (exact)
#define NORM_DIV 61.03515625f
#define MAX_RATE 2.5f
#define MIN_RATE 0.4f   // 1/2.5 exactly

// Plain global_atomic_add_f32 with NO sc0/sc1 bits: executes in the local
// XCD's L2 (TCC) instead of being forwarded memory-side. Atomic w.r.t.
// everything routed through that L2 (= the whole XCD).
__device__ __forceinline__ void l2_atomic_add(float* addr, float val) {
    asm volatile("global_atomic_add_f32 %0, %1, off"
                 :: "v"(addr), "v"(val) : "memory");
}

__device__ __forceinline__ unsigned int xcc_id() {
    unsigned int x;
    asm volatile("s_getreg_b32 %0, hwreg(HW_REG_XCC_ID)" : "=s"(x));
    return x & (NXCD - 1);
}

// ---- main path: per-XCD replicated accumulators in d_ws ----

__global__ __launch_bounds__(256) void pin_scatter_xcd_kernel(
        const float* __restrict__ pos,        // [2*NUM_NODES]: x then y
        const float* __restrict__ node_size_x,
        const float* __restrict__ node_size_y,
        const float* __restrict__ pin_weights,
        float* __restrict__ ws_acc)           // [NXCD][NBINS] raw sums
{
    int i = blockIdx.x * blockDim.x + threadIdx.x;
    if (i >= NUM_PHYSICAL) return;

    float* acc = ws_acc + (size_t)xcc_id() * NBINS;

    float sx = node_size_x[i];
    float sy = node_size_y[i];
    float hx = 0.5f * fmaxf(sx, 2.0f * HALF_STRETCH);
    float hy = 0.5f * fmaxf(sy, 2.0f * HALF_STRETCH);
    float cx = pos[i]             + 0.5f * sx;
    float cy = pos[NUM_NODES + i] + 0.5f * sy;
    float x_min = cx - hx, x_max = cx + hx;
    float y_min = cy - hy, y_max = cy + hy;
    float density = pin_weights[i] / (4.0f * hx * hy);

    int bxl = (int)floorf(x_min / BSX);
    int byl = (int)floorf(y_min / BSY);

    // Span 2*hx <= 3 < 2*BSX => at most 3 bins per axis; the reference's
    // kx=3/ky=3 iterations always fail the ox>0/oy>0 mask.
    #pragma unroll
    for (int kx = 0; kx < 3; ++kx) {
        int ix = bxl + kx;
        float bx_lo = (float)ix * BSX;
        float ox = fminf(x_max, bx_lo + BSX) - fmaxf(x_min, bx_lo);
        if (ix < 0 || ix >= NBX || !(ox > 0.0f)) continue;
        #pragma unroll
        for (int ky = 0; ky < 3; ++ky) {
            int iy = byl + ky;
            float by_lo = (float)iy * BSY;
            float oy = fminf(y_max, by_lo + BSY) - fmaxf(y_min, by_lo);
            if (iy >= 0 && iy < NBY && oy > 0.0f) {
                l2_atomic_add(&acc[ix * NBY + iy], ox * oy * density);
            }
        }
    }
    // Drain outstanding atomics before wave exit (inline asm is invisible
    // to the compiler's waitcnt insertion).
    asm volatile("s_waitcnt vmcnt(0)");
}

__global__ void reduce_finalize_kernel(const float* __restrict__ ws_acc,
                                       float* __restrict__ out, int n) {
    int i = blockIdx.x * blockDim.x + threadIdx.x;
    if (i < n) {
        float s = 0.0f;
        #pragma unroll
        for (int k = 0; k < NXCD; ++k) s += ws_acc[(size_t)k * n + i];
        float u = s / NORM_DIV;
        out[i] = fminf(fmaxf(u, MIN_RATE), MAX_RATE);
    }
}

// ---- fallback path (ws too small): proven device-scope atomics into d_out ----

__global__ void zero_acc_kernel(float* __restrict__ acc, int n) {
    int i = blockIdx.x * blockDim.x + threadIdx.x;
    if (i < n) acc[i] = 0.0f;
}

__global__ __launch_bounds__(256) void pin_scatter_kernel(
        const float* __restrict__ pos,
        const float* __restrict__ node_size_x,
        const float* __restrict__ node_size_y,
        const float* __restrict__ pin_weights,
        float* __restrict__ acc)
{
    int i = blockIdx.x * blockDim.x + threadIdx.x;
    if (i >= NUM_PHYSICAL) return;

    float sx = node_size_x[i];
    float sy = node_size_y[i];
    float hx = 0.5f * fmaxf(sx, 2.0f * HALF_STRETCH);
    float hy = 0.5f * fmaxf(sy, 2.0f * HALF_STRETCH);
    float cx = pos[i]             + 0.5f * sx;
    float cy = pos[NUM_NODES + i] + 0.5f * sy;
    float x_min = cx - hx, x_max = cx + hx;
    float y_min = cy - hy, y_max = cy + hy;
    float density = pin_weights[i] / (4.0f * hx * hy);

    int bxl = (int)floorf(x_min / BSX);
    int byl = (int)floorf(y_min / BSY);

    #pragma unroll
    for (int kx = 0; kx < 3; ++kx) {
        int ix = bxl + kx;
        float bx_lo = (float)ix * BSX;
        float ox = fminf(x_max, bx_lo + BSX) - fmaxf(x_min, bx_lo);
        if (ix < 0 || ix >= NBX || !(ox > 0.0f)) continue;
        #pragma unroll
        for (int ky = 0; ky < 3; ++ky) {
            int iy = byl + ky;
            float by_lo = (float)iy * BSY;
            float oy = fminf(y_max, by_lo + BSY) - fmaxf(y_min, by_lo);
            if (iy >= 0 && iy < NBY && oy > 0.0f) {
                atomicAdd(&acc[ix * NBY + iy], ox * oy * density);
            }
        }
    }
}

__global__ void finalize_kernel(float* __restrict__ out, int n) {
    int i = blockIdx.x * blockDim.x + threadIdx.x;
    if (i < n) {
        float u = out[i] / NORM_DIV;
        u = fminf(fmaxf(u, MIN_RATE), MAX_RATE);
        out[i] = u;
    }
}

extern "C" void kernel_launch(void* const* d_in, const int* in_sizes, int n_in,
                              void* d_out, int out_size, void* d_ws, size_t ws_size,
                              hipStream_t stream) {
    const float* pos          = (const float*)d_in[0];
    const float* node_size_x  = (const float*)d_in[1];
    const float* node_size_y  = (const float*)d_in[2];
    const float* pin_weights  = (const float*)d_in[3];
    float* out = (float*)d_out;

    const size_t repl_bytes = (size_t)NXCD * NBINS * sizeof(float);

    if (ws_size >= repl_bytes) {
        // zero the 8 per-XCD accumulator copies (every launch; replays
        // don't re-poison)
        hipMemsetAsync(d_ws, 0, repl_bytes, stream);

        pin_scatter_xcd_kernel<<<(NUM_PHYSICAL + 255) / 256, 256, 0, stream>>>(
            pos, node_size_x, node_size_y, pin_weights, (float*)d_ws);

        reduce_finalize_kernel<<<(NBINS + 255) / 256, 256, 0, stream>>>(
            (const float*)d_ws, out, NBINS);
    } else {
        zero_acc_kernel<<<(NBINS + 255) / 256, 256, 0, stream>>>(out, NBINS);
        pin_scatter_kernel<<<(NUM_PHYSICAL + 255) / 256, 256, 0, stream>>>(
            pos, node_size_x, node_size_y, pin_weights, out);
        finalize_kernel<<<(NBINS + 255) / 256, 256, 0, stream>>>(out, NBINS);
    }
}

// Round 4
// 145.236 us; speedup vs baseline: 4.0314x; 4.0314x over previous
//
#include <hip/hip_runtime.h>

// Problem constants (must match reference)
#define NUM_PHYSICAL 2000000
#define NUM_NODES    2500000   // 2,000,000 physical + 500,000 filler
#define NBX 512
#define NBY 512
#define NBINS (NBX * NBY)

// BSX = BSY = 1000/512 = 1.953125 (exact in binary)
#define BSX 1.953125f
#define HALF_STRETCH ((float)(0.5 * 1.953125 * 1.4142135623730951))
// BSX*BSY*UNIT_PIN_CAPACITY = 61.03515625 (exact)
#define NORM_DIV 61.03515625f
#define MAX_RATE 2.5f
#define MIN_RATE 0.4f   // 1/2.5 exactly

// Tiling for the sort: 16x16 bins per tile -> 32x32 = 1024 tiles.
#define T 16
#define NTX 32
#define NTY 32
#define NT (NTX * NTY)
#define TS 18                  // T+2 halo (a node spans <= 3 bins/axis)
#define TILE_CELLS (TS * TS)   // 324
#define HB 512                 // blocks for hist/placement
#define CHUNK ((NUM_PHYSICAL + HB - 1) / HB)   // 3907

// clamped tile coordinate from a (possibly out-of-range) bin index
__device__ __forceinline__ int tile_coord(int b) {
    return (min(max(b, 0), NBX - 1)) >> 4;
}

// geometry shared by hist/placement (must be bit-identical in both)
__device__ __forceinline__ void node_box(const float* __restrict__ pos,
                                         const float* __restrict__ nsx,
                                         const float* __restrict__ nsy, int i,
                                         float& x_min, float& y_min,
                                         float& x_max, float& y_max,
                                         float& hx, float& hy) {
    float sx = nsx[i], sy = nsy[i];
    hx = 0.5f * fmaxf(sx, 2.0f * HALF_STRETCH);
    hy = 0.5f * fmaxf(sy, 2.0f * HALF_STRETCH);
    float cx = pos[i]             + 0.5f * sx;
    float cy = pos[NUM_NODES + i] + 0.5f * sy;
    x_min = cx - hx; x_max = cx + hx;
    y_min = cy - hy; y_max = cy + hy;
}

// ---------------- sorted path ----------------

// K1: per-block histogram of nodes per tile
__global__ __launch_bounds__(256) void hist_kernel(
        const float* __restrict__ pos, const float* __restrict__ nsx,
        const float* __restrict__ nsy, int* __restrict__ hist_part) {
    __shared__ int lh[NT];
    int tid = threadIdx.x, b = blockIdx.x;
    for (int j = tid; j < NT; j += 256) lh[j] = 0;
    __syncthreads();
    int lo = b * CHUNK, hi = min(lo + CHUNK, NUM_PHYSICAL);
    for (int i = lo + tid; i < hi; i += 256) {
        float x_min, y_min, x_max, y_max, hx, hy;
        node_box(pos, nsx, nsy, i, x_min, y_min, x_max, y_max, hx, hy);
        int bxl = (int)floorf(x_min / BSX);
        int byl = (int)floorf(y_min / BSX);
        int t = tile_coord(bxl) * NTY + tile_coord(byl);
        atomicAdd(&lh[t], 1);
    }
    __syncthreads();
    for (int j = tid; j < NT; j += 256) hist_part[b * NT + j] = lh[j];
}

// K2a: for each tile, exclusive prefix over the HB blocks' counts
__global__ __launch_bounds__(512) void scan_blocks_kernel(
        const int* __restrict__ hist_part, int* __restrict__ off_part,
        int* __restrict__ tile_total) {
    __shared__ int sc[2][HB];
    int t = blockIdx.x, b = threadIdx.x;
    int v = hist_part[b * NT + t];
    sc[0][b] = v;
    int src = 0;
    for (int off = 1; off < HB; off <<= 1) {
        __syncthreads();
        int x = sc[src][b];
        if (b >= off) x += sc[src][b - off];
        sc[src ^ 1][b] = x;
        src ^= 1;
    }
    __syncthreads();
    int incl = sc[src][b];
    off_part[b * NT + t] = incl - v;   // exclusive prefix
    if (b == HB - 1) tile_total[t] = incl;
}

// K2b: exclusive prefix over the 1024 tile totals
__global__ __launch_bounds__(1024) void scan_tiles_kernel(
        const int* __restrict__ tile_total, int* __restrict__ tile_start) {
    __shared__ int sc[2][NT];
    int t = threadIdx.x;
    int v = tile_total[t];
    sc[0][t] = v;
    int src = 0;
    for (int off = 1; off < NT; off <<= 1) {
        __syncthreads();
        int x = sc[src][t];
        if (t >= off) x += sc[src][t - off];
        sc[src ^ 1][t] = x;
        src ^= 1;
    }
    __syncthreads();
    int incl = sc[src][t];
    tile_start[t] = incl - v;
    if (t == NT - 1) tile_start[NT] = incl;
}

// K3: place each node's payload at its sorted position
__global__ __launch_bounds__(256) void place_kernel(
        const float* __restrict__ pos, const float* __restrict__ nsx,
        const float* __restrict__ nsy, const float* __restrict__ pw,
        const int* __restrict__ off_part, const int* __restrict__ tile_start,
        float4* __restrict__ pay4, float* __restrict__ payd) {
    __shared__ int lcur[NT];
    int tid = threadIdx.x, b = blockIdx.x;
    for (int j = tid; j < NT; j += 256)
        lcur[j] = tile_start[j] + off_part[b * NT + j];
    __syncthreads();
    int lo = b * CHUNK, hi = min(lo + CHUNK, NUM_PHYSICAL);
    for (int i = lo + tid; i < hi; i += 256) {
        float x_min, y_min, x_max, y_max, hx, hy;
        node_box(pos, nsx, nsy, i, x_min, y_min, x_max, y_max, hx, hy);
        int bxl = (int)floorf(x_min / BSX);
        int byl = (int)floorf(y_min / BSX);
        int t = tile_coord(bxl) * NTY + tile_coord(byl);
        int p = atomicAdd(&lcur[t], 1);
        pay4[p] = make_float4(x_min, y_min, x_max, y_max);
        payd[p] = pw[i] / (4.0f * hx * hy);
    }
}

// K4: one block per tile; accumulate into an 18x18 LDS tile, store (no atomics)
__global__ __launch_bounds__(256) void tile_scatter_kernel(
        const float4* __restrict__ pay4, const float* __restrict__ payd,
        const int* __restrict__ tile_start, float* __restrict__ tile_acc) {
    __shared__ float lacc[TILE_CELLS];
    int tid = threadIdx.x, t = blockIdx.x;
    int tx = t / NTY, ty = t % NTY;
    for (int j = tid; j < TILE_CELLS; j += 256) lacc[j] = 0.0f;
    __syncthreads();
    int lo = tile_start[t], hi = tile_start[t + 1];
    int bx0 = tx * T, by0 = ty * T;
    for (int p = lo + tid; p < hi; p += 256) {
        float4 g = pay4[p];
        float den = payd[p];
        float x_min = g.x, y_min = g.y, x_max = g.z, y_max = g.w;
        int bxl = (int)floorf(x_min / BSX);
        int byl = (int)floorf(y_min / BSX);
        #pragma unroll
        for (int kx = 0; kx < 3; ++kx) {
            int ix = bxl + kx;
            float bx_lo = (float)ix * BSX;
            float ox = fminf(x_max, bx_lo + BSX) - fmaxf(x_min, bx_lo);
            if (ix < 0 || ix >= NBX || !(ox > 0.0f)) continue;
            #pragma unroll
            for (int ky = 0; ky < 3; ++ky) {
                int iy = byl + ky;
                float by_lo = (float)iy * BSX;
                float oy = fminf(y_max, by_lo + BSX) - fmaxf(y_min, by_lo);
                if (iy >= 0 && iy < NBY && oy > 0.0f) {
                    // ix-bx0 in [0,17], iy-by0 in [0,17] by construction
                    atomicAdd(&lacc[(ix - bx0) * TS + (iy - by0)], ox * oy * den);
                }
            }
        }
    }
    __syncthreads();
    for (int j = tid; j < TILE_CELLS; j += 256)
        tile_acc[t * TILE_CELLS + j] = lacc[j];
}

// K5: gather each bin's <=4 halo contributions, scale, clip
__global__ __launch_bounds__(256) void final_kernel(
        const float* __restrict__ tile_acc, float* __restrict__ out) {
    int i = blockIdx.x * 256 + threadIdx.x;
    if (i >= NBINS) return;
    int ix = i / NBY, iy = i % NBY;
    int tx = ix >> 4, ty = iy >> 4;
    int lx = ix & 15, ly = iy & 15;
    float s = tile_acc[(tx * NTY + ty) * TILE_CELLS + lx * TS + ly];
    if (lx < 2 && tx > 0)
        s += tile_acc[((tx - 1) * NTY + ty) * TILE_CELLS + (lx + T) * TS + ly];
    if (ly < 2 && ty > 0)
        s += tile_acc[(tx * NTY + ty - 1) * TILE_CELLS + lx * TS + (ly + T)];
    if (lx < 2 && ly < 2 && tx > 0 && ty > 0)
        s += tile_acc[((tx - 1) * NTY + ty - 1) * TILE_CELLS + (lx + T) * TS + (ly + T)];
    float u = s / NORM_DIV;
    out[i] = fminf(fmaxf(u, MIN_RATE), MAX_RATE);
}

// ---------------- fallback path (proven, 585 us) ----------------

__global__ void zero_acc_kernel(float* __restrict__ acc, int n) {
    int i = blockIdx.x * blockDim.x + threadIdx.x;
    if (i < n) acc[i] = 0.0f;
}

__global__ __launch_bounds__(256) void pin_scatter_kernel(
        const float* __restrict__ pos, const float* __restrict__ nsx,
        const float* __restrict__ nsy, const float* __restrict__ pw,
        float* __restrict__ acc) {
    int i = blockIdx.x * blockDim.x + threadIdx.x;
    if (i >= NUM_PHYSICAL) return;
    float x_min, y_min, x_max, y_max, hx, hy;
    node_box(pos, nsx, nsy, i, x_min, y_min, x_max, y_max, hx, hy);
    float density = pw[i] / (4.0f * hx * hy);
    int bxl = (int)floorf(x_min / BSX);
    int byl = (int)floorf(y_min / BSX);
    #pragma unroll
    for (int kx = 0; kx < 3; ++kx) {
        int ix = bxl + kx;
        float bx_lo = (float)ix * BSX;
        float ox = fminf(x_max, bx_lo + BSX) - fmaxf(x_min, bx_lo);
        if (ix < 0 || ix >= NBX || !(ox > 0.0f)) continue;
        #pragma unroll
        for (int ky = 0; ky < 3; ++ky) {
            int iy = byl + ky;
            float by_lo = (float)iy * BSX;
            float oy = fminf(y_max, by_lo + BSX) - fmaxf(y_min, by_lo);
            if (iy >= 0 && iy < NBY && oy > 0.0f)
                atomicAdd(&acc[ix * NBY + iy], ox * oy * density);
        }
    }
}

__global__ void finalize_kernel(float* __restrict__ out, int n) {
    int i = blockIdx.x * blockDim.x + threadIdx.x;
    if (i < n) {
        float u = out[i] / NORM_DIV;
        out[i] = fminf(fmaxf(u, MIN_RATE), MAX_RATE);
    }
}

extern "C" void kernel_launch(void* const* d_in, const int* in_sizes, int n_in,
                              void* d_out, int out_size, void* d_ws, size_t ws_size,
                              hipStream_t stream) {
    const float* pos = (const float*)d_in[0];
    const float* nsx = (const float*)d_in[1];
    const float* nsy = (const float*)d_in[2];
    const float* pw  = (const float*)d_in[3];
    float* out = (float*)d_out;

    // workspace layout (bytes)
    const size_t OFF_PAY4  = 0;                          // 2M float4 = 32,000,000
    const size_t OFF_PAYD  = 32000000;                   // 2M float  =  8,000,000
    const size_t OFF_HIST  = 40000000;                   // HB*NT int =  2,097,152
    const size_t OFF_OFFP  = 42097152;                   // HB*NT int =  2,097,152
    const size_t OFF_TTOT  = 44194304;                   // NT int    =      4,096
    const size_t OFF_TSTR  = 44198400;                   // (NT+1) int=      4,100
    const size_t OFF_TACC  = 44202504;                   // NT*324 f  =  1,327,104
    const size_t WS_NEEDED = OFF_TACC + (size_t)NT * TILE_CELLS * sizeof(float);

    if (ws_size >= WS_NEEDED) {
        char* w = (char*)d_ws;
        float4* pay4     = (float4*)(w + OFF_PAY4);
        float*  payd     = (float*) (w + OFF_PAYD);
        int*    hist_part= (int*)   (w + OFF_HIST);
        int*    off_part = (int*)   (w + OFF_OFFP);
        int*    tile_tot = (int*)   (w + OFF_TTOT);
        int*    tile_str = (int*)   (w + OFF_TSTR);
        float*  tile_acc = (float*) (w + OFF_TACC);

        hist_kernel<<<HB, 256, 0, stream>>>(pos, nsx, nsy, hist_part);
        scan_blocks_kernel<<<NT, 512, 0, stream>>>(hist_part, off_part, tile_tot);
        scan_tiles_kernel<<<1, NT, 0, stream>>>(tile_tot, tile_str);
        place_kernel<<<HB, 256, 0, stream>>>(pos, nsx, nsy, pw,
                                             off_part, tile_str, pay4, payd);
        tile_scatter_kernel<<<NT, 256, 0, stream>>>(pay4, payd, tile_str, tile_acc);
        final_kernel<<<(NBINS + 255) / 256, 256, 0, stream>>>(tile_acc, out);
    } else {
        zero_acc_kernel<<<(NBINS + 255) / 256, 256, 0, stream>>>(out, NBINS);
        pin_scatter_kernel<<<(NUM_PHYSICAL + 255) / 256, 256, 0, stream>>>(
            pos, nsx, nsy, pw, out);
        finalize_kernel<<<(NBINS + 255) / 256, 256, 0, stream>>>(out, NBINS);
    }
}

// Round 5
// 98.569 us; speedup vs baseline: 5.9401x; 1.4735x over previous
//
#include <hip/hip_runtime.h>
#include <hip/hip_fp16.h>

// Problem constants (must match reference)
#define NUM_PHYSICAL 2000000
#define NUM_NODES    2500000   // 2,000,000 physical + 500,000 filler
#define NBX 512
#define NBY 512
#define NBINS (NBX * NBY)

// BSX = BSY = 1000/512 = 1.953125 (exact in binary)
#define BSX 1.953125f
#define HALF_STRETCH ((float)(0.5 * 1.953125 * 1.4142135623730951))
// BSX*BSY*UNIT_PIN_CAPACITY = 61.03515625 (exact)
#define NORM_DIV 61.03515625f
#define MAX_RATE 2.5f
#define MIN_RATE 0.4f   // 1/2.5 exactly

// Strip bucketing: 64 strips of 8 y-rows each.
#define NSTRIP 64
#define SROWS 8                  // rows per strip
#define LROWS (SROWS + 2)        // +2 y-halo (node spans <=3 rows)
#define SCELLS (LROWS * NBX)     // 5120 floats = 20 KB LDS
#define RREP 8                   // scatter replicas per strip
#define SCAT_BLOCKS (NSTRIP * RREP)
#define HB 1024                  // blocks for hist/placement
#define CHUNK ((NUM_PHYSICAL + HB - 1) / HB)   // 1954

__device__ __forceinline__ int strip_of(float y_min) {
    int byl = (int)floorf(y_min / BSX);
    return (min(max(byl, 0), NBY - 1)) >> 3;
}

__device__ __forceinline__ void node_box(const float* __restrict__ pos,
                                         const float* __restrict__ nsx,
                                         const float* __restrict__ nsy, int i,
                                         float& x_min, float& y_min,
                                         float& hx, float& hy) {
    float sx = nsx[i], sy = nsy[i];
    hx = 0.5f * fmaxf(sx, 2.0f * HALF_STRETCH);
    hy = 0.5f * fmaxf(sy, 2.0f * HALF_STRETCH);
    x_min = (pos[i]             + 0.5f * sx) - hx;
    y_min = (pos[NUM_NODES + i] + 0.5f * sy) - hy;
}

__device__ __forceinline__ float pack_hxy(float hx, float hy) {
    unsigned int u = ((unsigned int)__half_as_ushort(__float2half_rn(hy)) << 16)
                   |  (unsigned int)__half_as_ushort(__float2half_rn(hx));
    return __uint_as_float(u);
}
__device__ __forceinline__ void unpack_hxy(float p, float& hx, float& hy) {
    unsigned int u = __float_as_uint(p);
    hx = __half2float(__ushort_as_half((unsigned short)(u & 0xffffu)));
    hy = __half2float(__ushort_as_half((unsigned short)(u >> 16)));
}

// ---------------- sorted-strip path ----------------

// K1: per-block strip histogram (y data only)
__global__ __launch_bounds__(256) void hist_kernel(
        const float* __restrict__ pos, const float* __restrict__ nsy,
        int* __restrict__ hist_part) {
    __shared__ int lh[NSTRIP];
    int tid = threadIdx.x, b = blockIdx.x;
    if (tid < NSTRIP) lh[tid] = 0;
    __syncthreads();
    int lo = b * CHUNK, hi = min(lo + CHUNK, NUM_PHYSICAL);
    for (int i = lo + tid; i < hi; i += 256) {
        float sy = nsy[i];
        float hy = 0.5f * fmaxf(sy, 2.0f * HALF_STRETCH);
        float y_min = (pos[NUM_NODES + i] + 0.5f * sy) - hy;
        atomicAdd(&lh[strip_of(y_min)], 1);
    }
    __syncthreads();
    if (tid < NSTRIP) hist_part[b * NSTRIP + tid] = lh[tid];
}

// K2a: per strip, exclusive prefix over the HB blocks' counts
__global__ __launch_bounds__(1024) void scan_blocks_kernel(
        const int* __restrict__ hist_part, int* __restrict__ off_part,
        int* __restrict__ strip_total) {
    __shared__ int sc[2][HB];
    int s = blockIdx.x, b = threadIdx.x;
    int v = hist_part[b * NSTRIP + s];
    sc[0][b] = v;
    int src = 0;
    for (int off = 1; off < HB; off <<= 1) {
        __syncthreads();
        int x = sc[src][b];
        if (b >= off) x += sc[src][b - off];
        sc[src ^ 1][b] = x;
        src ^= 1;
    }
    __syncthreads();
    int incl = sc[src][b];
    off_part[b * NSTRIP + s] = incl - v;   // exclusive prefix
    if (b == HB - 1) strip_total[s] = incl;
}

// K2b: exclusive prefix over the 64 strip totals
__global__ __launch_bounds__(64) void scan_strips_kernel(
        const int* __restrict__ strip_total, int* __restrict__ strip_start) {
    __shared__ int sc[2][NSTRIP];
    int t = threadIdx.x;
    int v = strip_total[t];
    sc[0][t] = v;
    int src = 0;
    for (int off = 1; off < NSTRIP; off <<= 1) {
        __syncthreads();
        int x = sc[src][t];
        if (t >= off) x += sc[src][t - off];
        sc[src ^ 1][t] = x;
        src ^= 1;
    }
    __syncthreads();
    int incl = sc[src][t];
    strip_start[t] = incl - v;
    if (t == NSTRIP - 1) strip_start[NSTRIP] = incl;
}

// K3: place compressed 16B payloads at sorted positions (deterministic slots,
// no global atomics — per-block cursors are exact from the scans)
__global__ __launch_bounds__(256) void place_kernel(
        const float* __restrict__ pos, const float* __restrict__ nsx,
        const float* __restrict__ nsy, const float* __restrict__ pw,
        const int* __restrict__ off_part, const int* __restrict__ strip_start,
        float4* __restrict__ pay) {
    __shared__ int lcur[NSTRIP];
    int tid = threadIdx.x, b = blockIdx.x;
    if (tid < NSTRIP) lcur[tid] = strip_start[tid] + off_part[b * NSTRIP + tid];
    __syncthreads();
    int lo = b * CHUNK, hi = min(lo + CHUNK, NUM_PHYSICAL);
    for (int i = lo + tid; i < hi; i += 256) {
        float x_min, y_min, hx, hy;
        node_box(pos, nsx, nsy, i, x_min, y_min, hx, hy);
        float density = pw[i] / (4.0f * hx * hy);
        int s = strip_of(y_min);
        int p = atomicAdd(&lcur[s], 1);
        pay[p] = make_float4(x_min, y_min, pack_hxy(hx, hy), density);
    }
}

// K4: strip scatter — LDS accumulate (8+2 rows x 512 cols), plain stores
__global__ __launch_bounds__(512) void strip_scatter_kernel(
        const float4* __restrict__ pay, const int* __restrict__ strip_start,
        float* __restrict__ partial) {
    __shared__ float lacc[SCELLS];
    int tid = threadIdx.x;
    int s = blockIdx.x >> 3, r = blockIdx.x & (RREP - 1);
    for (int j = tid; j < SCELLS; j += 512) lacc[j] = 0.0f;
    __syncthreads();
    int lo0 = strip_start[s], count = strip_start[s + 1] - lo0;
    int lo = lo0 + (int)(((long long)count * r) / RREP);
    int hi = lo0 + (int)(((long long)count * (r + 1)) / RREP);
    int row0 = s * SROWS;
    for (int p = lo + tid; p < hi; p += 512) {
        float4 g = pay[p];
        float x_min = g.x, y_min = g.y, den = g.w;
        float hx, hy;
        unpack_hxy(g.z, hx, hy);
        float x_max = x_min + 2.0f * hx;
        float y_max = y_min + 2.0f * hy;
        int bxl = (int)floorf(x_min / BSX);
        int byl = (int)floorf(y_min / BSX);
        #pragma unroll
        for (int ky = 0; ky < 3; ++ky) {
            int iy = byl + ky;
            float by_lo = (float)iy * BSX;
            float oy = fminf(y_max, by_lo + BSX) - fmaxf(y_min, by_lo);
            int L = iy - row0;
            if (iy < 0 || iy >= NBY || L < 0 || L >= LROWS || !(oy > 0.0f)) continue;
            #pragma unroll
            for (int kx = 0; kx < 3; ++kx) {
                int ix = bxl + kx;
                float bx_lo = (float)ix * BSX;
                float ox = fminf(x_max, bx_lo + BSX) - fmaxf(x_min, bx_lo);
                if (ix >= 0 && ix < NBX && ox > 0.0f)
                    atomicAdd(&lacc[L * NBX + ix], ox * oy * den);
            }
        }
    }
    __syncthreads();
    float* dst = partial + (size_t)blockIdx.x * SCELLS;
    for (int j = tid; j < SCELLS; j += 512) dst[j] = lacc[j];
}

// K5: gather replicas + y-halo, scale, clip; transpose via LDS so both the
// partial reads (contiguous x) and out writes ([x][y] layout) are coalesced
__global__ __launch_bounds__(1024) void final_kernel(
        const float* __restrict__ partial, float* __restrict__ out) {
    __shared__ float tile[32][33];
    int tx = threadIdx.x, ty = threadIdx.y;
    int x0 = blockIdx.x * 32, y0 = blockIdx.y * 32;
    int x = x0 + tx;          // x-bin (contiguous over lanes)
    int gy = y0 + ty;         // y-bin
    int s = gy >> 3, L = gy & 7;
    float sum = 0.0f;
    #pragma unroll
    for (int r = 0; r < RREP; ++r)
        sum += partial[(size_t)(s * RREP + r) * SCELLS + L * NBX + x];
    if (L < 2 && s > 0) {
        #pragma unroll
        for (int r = 0; r < RREP; ++r)
            sum += partial[(size_t)((s - 1) * RREP + r) * SCELLS + (L + SROWS) * NBX + x];
    }
    float u = sum / NORM_DIV;
    tile[ty][tx] = fminf(fmaxf(u, MIN_RATE), MAX_RATE);
    __syncthreads();
    // out[(x0+ty)*NBY + (y0+tx)] = tile[tx][ty]
    out[(x0 + ty) * NBY + (y0 + tx)] = tile[tx][ty];
}

// ---------------- fallback path (proven) ----------------

__global__ void zero_acc_kernel(float* __restrict__ acc, int n) {
    int i = blockIdx.x * blockDim.x + threadIdx.x;
    if (i < n) acc[i] = 0.0f;
}

__global__ __launch_bounds__(256) void pin_scatter_kernel(
        const float* __restrict__ pos, const float* __restrict__ nsx,
        const float* __restrict__ nsy, const float* __restrict__ pw,
        float* __restrict__ acc) {
    int i = blockIdx.x * blockDim.x + threadIdx.x;
    if (i >= NUM_PHYSICAL) return;
    float x_min, y_min, hx, hy;
    node_box(pos, nsx, nsy, i, x_min, y_min, hx, hy);
    float x_max = x_min + 2.0f * hx, y_max = y_min + 2.0f * hy;
    float density = pw[i] / (4.0f * hx * hy);
    int bxl = (int)floorf(x_min / BSX);
    int byl = (int)floorf(y_min / BSX);
    #pragma unroll
    for (int kx = 0; kx < 3; ++kx) {
        int ix = bxl + kx;
        float bx_lo = (float)ix * BSX;
        float ox = fminf(x_max, bx_lo + BSX) - fmaxf(x_min, bx_lo);
        if (ix < 0 || ix >= NBX || !(ox > 0.0f)) continue;
        #pragma unroll
        for (int ky = 0; ky < 3; ++ky) {
            int iy = byl + ky;
            float by_lo = (float)iy * BSX;
            float oy = fminf(y_max, by_lo + BSX) - fmaxf(y_min, by_lo);
            if (iy >= 0 && iy < NBY && oy > 0.0f)
                atomicAdd(&acc[ix * NBY + iy], ox * oy * density);
        }
    }
}

__global__ void finalize_kernel(float* __restrict__ out, int n) {
    int i = blockIdx.x * blockDim.x + threadIdx.x;
    if (i < n) {
        float u = out[i] / NORM_DIV;
        out[i] = fminf(fmaxf(u, MIN_RATE), MAX_RATE);
    }
}

extern "C" void kernel_launch(void* const* d_in, const int* in_sizes, int n_in,
                              void* d_out, int out_size, void* d_ws, size_t ws_size,
                              hipStream_t stream) {
    const float* pos = (const float*)d_in[0];
    const float* nsx = (const float*)d_in[1];
    const float* nsy = (const float*)d_in[2];
    const float* pw  = (const float*)d_in[3];
    float* out = (float*)d_out;

    // workspace layout (bytes)
    const size_t OFF_PAY  = 0;                                   // 2M float4 = 32,000,000
    const size_t OFF_HIST = 32000000;                            // HB*NSTRIP int = 262,144
    const size_t OFF_OFFP = OFF_HIST + (size_t)HB * NSTRIP * 4;  // 262,144
    const size_t OFF_TTOT = OFF_OFFP + (size_t)HB * NSTRIP * 4;  // 256
    const size_t OFF_TSTR = OFF_TTOT + NSTRIP * 4;               // 260
    const size_t OFF_PART = (OFF_TSTR + (NSTRIP + 1) * 4 + 255) & ~(size_t)255;
    const size_t WS_NEEDED = OFF_PART + (size_t)SCAT_BLOCKS * SCELLS * 4; // ~43.0 MB

    if (ws_size >= WS_NEEDED) {
        char* w = (char*)d_ws;
        float4* pay      = (float4*)(w + OFF_PAY);
        int*    hist_prt = (int*)   (w + OFF_HIST);
        int*    off_part = (int*)   (w + OFF_OFFP);
        int*    strip_tt = (int*)   (w + OFF_TTOT);
        int*    strip_st = (int*)   (w + OFF_TSTR);
        float*  partial  = (float*) (w + OFF_PART);

        hist_kernel<<<HB, 256, 0, stream>>>(pos, nsy, hist_prt);
        scan_blocks_kernel<<<NSTRIP, HB, 0, stream>>>(hist_prt, off_part, strip_tt);
        scan_strips_kernel<<<1, NSTRIP, 0, stream>>>(strip_tt, strip_st);
        place_kernel<<<HB, 256, 0, stream>>>(pos, nsx, nsy, pw,
                                             off_part, strip_st, pay);
        strip_scatter_kernel<<<SCAT_BLOCKS, 512, 0, stream>>>(pay, strip_st, partial);
        final_kernel<<<dim3(NBX / 32, NBY / 32), dim3(32, 32), 0, stream>>>(partial, out);
    } else {
        zero_acc_kernel<<<(NBINS + 255) / 256, 256, 0, stream>>>(out, NBINS);
        pin_scatter_kernel<<<(NUM_PHYSICAL + 255) / 256, 256, 0, stream>>>(
            pos, nsx, nsy, pw, out);
        finalize_kernel<<<(NBINS + 255) / 256, 256, 0, stream>>>(out, NBINS);
    }
}

// Round 6
// 98.457 us; speedup vs baseline: 5.9469x; 1.0011x over previous
//
#include <hip/hip_runtime.h>
#include <hip/hip_fp16.h>

// Problem constants (must match reference)
#define NUM_PHYSICAL 2000000
#define NUM_NODES    2500000   // 2,000,000 physical + 500,000 filler
#define NBX 512
#define NBY 512
#define NBINS (NBX * NBY)

// BSX = BSY = 1000/512 = 1.953125 (exact in binary)
#define BSX 1.953125f
#define HALF_STRETCH ((float)(0.5 * 1.953125 * 1.4142135623730951))
// BSX*BSY*UNIT_PIN_CAPACITY = 61.03515625 (exact)
#define NORM_DIV 61.03515625f
#define MAX_RATE 2.5f
#define MIN_RATE 0.4f   // 1/2.5 exactly

// Strip bucketing: 64 strips of 8 y-rows each.
#define NSTRIP 64
#define SROWS 8                  // rows per strip
#define LROWS (SROWS + 2)        // +2 y-halo (node spans <=3 rows)
#define SCELLS (LROWS * NBX)     // 5120 floats = 20 KB LDS
#define RREP 8                   // scatter replicas per strip
#define SCAT_BLOCKS (NSTRIP * RREP)
#define SCAT_THREADS 1024        // 16 waves/block -> 2 blocks/CU = 32 waves/CU
#define HB 1024                  // blocks for hist/placement
#define CHUNK ((NUM_PHYSICAL + HB - 1) / HB)   // 1954

__device__ __forceinline__ int strip_of(float y_min) {
    int byl = (int)floorf(y_min / BSX);
    return (min(max(byl, 0), NBY - 1)) >> 3;
}

__device__ __forceinline__ void node_box(const float* __restrict__ pos,
                                         const float* __restrict__ nsx,
                                         const float* __restrict__ nsy, int i,
                                         float& x_min, float& y_min,
                                         float& hx, float& hy) {
    float sx = nsx[i], sy = nsy[i];
    hx = 0.5f * fmaxf(sx, 2.0f * HALF_STRETCH);
    hy = 0.5f * fmaxf(sy, 2.0f * HALF_STRETCH);
    x_min = (pos[i]             + 0.5f * sx) - hx;
    y_min = (pos[NUM_NODES + i] + 0.5f * sy) - hy;
}

__device__ __forceinline__ float pack_hxy(float hx, float hy) {
    unsigned int u = ((unsigned int)__half_as_ushort(__float2half_rn(hy)) << 16)
                   |  (unsigned int)__half_as_ushort(__float2half_rn(hx));
    return __uint_as_float(u);
}
__device__ __forceinline__ void unpack_hxy(float p, float& hx, float& hy) {
    unsigned int u = __float_as_uint(p);
    hx = __half2float(__ushort_as_half((unsigned short)(u & 0xffffu)));
    hy = __half2float(__ushort_as_half((unsigned short)(u >> 16)));
}

// Native LDS f32 atomic (ds_add_f32), no CAS loop, no return value.
__device__ __forceinline__ void lds_add(float* addr, float val) {
#if defined(__HIP_DEVICE_COMPILE__)
    unsafeAtomicAdd(addr, val);
#else
    atomicAdd(addr, val);
#endif
}

// ---------------- sorted-strip path ----------------

// K1: per-block strip histogram (y data only)
__global__ __launch_bounds__(256) void hist_kernel(
        const float* __restrict__ pos, const float* __restrict__ nsy,
        int* __restrict__ hist_part) {
    __shared__ int lh[NSTRIP];
    int tid = threadIdx.x, b = blockIdx.x;
    if (tid < NSTRIP) lh[tid] = 0;
    __syncthreads();
    int lo = b * CHUNK, hi = min(lo + CHUNK, NUM_PHYSICAL);
    for (int i = lo + tid; i < hi; i += 256) {
        float sy = nsy[i];
        float hy = 0.5f * fmaxf(sy, 2.0f * HALF_STRETCH);
        float y_min = (pos[NUM_NODES + i] + 0.5f * sy) - hy;
        atomicAdd(&lh[strip_of(y_min)], 1);
    }
    __syncthreads();
    if (tid < NSTRIP) hist_part[b * NSTRIP + tid] = lh[tid];
}

// K2a: per strip, exclusive prefix over the HB blocks' counts
__global__ __launch_bounds__(1024) void scan_blocks_kernel(
        const int* __restrict__ hist_part, int* __restrict__ off_part,
        int* __restrict__ strip_total) {
    __shared__ int sc[2][HB];
    int s = blockIdx.x, b = threadIdx.x;
    int v = hist_part[b * NSTRIP + s];
    sc[0][b] = v;
    int src = 0;
    for (int off = 1; off < HB; off <<= 1) {
        __syncthreads();
        int x = sc[src][b];
        if (b >= off) x += sc[src][b - off];
        sc[src ^ 1][b] = x;
        src ^= 1;
    }
    __syncthreads();
    int incl = sc[src][b];
    off_part[b * NSTRIP + s] = incl - v;   // exclusive prefix
    if (b == HB - 1) strip_total[s] = incl;
}

// K2b: exclusive prefix over the 64 strip totals
__global__ __launch_bounds__(64) void scan_strips_kernel(
        const int* __restrict__ strip_total, int* __restrict__ strip_start) {
    __shared__ int sc[2][NSTRIP];
    int t = threadIdx.x;
    int v = strip_total[t];
    sc[0][t] = v;
    int src = 0;
    for (int off = 1; off < NSTRIP; off <<= 1) {
        __syncthreads();
        int x = sc[src][t];
        if (t >= off) x += sc[src][t - off];
        sc[src ^ 1][t] = x;
        src ^= 1;
    }
    __syncthreads();
    int incl = sc[src][t];
    strip_start[t] = incl - v;
    if (t == NSTRIP - 1) strip_start[NSTRIP] = incl;
}

// K3: place compressed 16B payloads at sorted positions (deterministic slots,
// no global atomics — per-block cursors are exact from the scans)
__global__ __launch_bounds__(256) void place_kernel(
        const float* __restrict__ pos, const float* __restrict__ nsx,
        const float* __restrict__ nsy, const float* __restrict__ pw,
        const int* __restrict__ off_part, const int* __restrict__ strip_start,
        float4* __restrict__ pay) {
    __shared__ int lcur[NSTRIP];
    int tid = threadIdx.x, b = blockIdx.x;
    if (tid < NSTRIP) lcur[tid] = strip_start[tid] + off_part[b * NSTRIP + tid];
    __syncthreads();
    int lo = b * CHUNK, hi = min(lo + CHUNK, NUM_PHYSICAL);
    for (int i = lo + tid; i < hi; i += 256) {
        float x_min, y_min, hx, hy;
        node_box(pos, nsx, nsy, i, x_min, y_min, hx, hy);
        float density = pw[i] / (4.0f * hx * hy);
        int s = strip_of(y_min);
        int p = atomicAdd(&lcur[s], 1);
        pay[p] = make_float4(x_min, y_min, pack_hxy(hx, hy), density);
    }
}

// K4: strip scatter — LDS accumulate (8+2 rows x 512 cols), plain stores.
// 1024 threads/block so 2 blocks/CU fill all 32 wave slots (latency hiding).
__global__ __launch_bounds__(SCAT_THREADS) void strip_scatter_kernel(
        const float4* __restrict__ pay, const int* __restrict__ strip_start,
        float* __restrict__ partial) {
    __shared__ float lacc[SCELLS];
    int tid = threadIdx.x;
    int s = blockIdx.x >> 3, r = blockIdx.x & (RREP - 1);
    for (int j = tid; j < SCELLS; j += SCAT_THREADS) lacc[j] = 0.0f;
    __syncthreads();
    int lo0 = strip_start[s], count = strip_start[s + 1] - lo0;
    int lo = lo0 + (int)(((long long)count * r) / RREP);
    int hi = lo0 + (int)(((long long)count * (r + 1)) / RREP);
    int row0 = s * SROWS;
    for (int p = lo + tid; p < hi; p += SCAT_THREADS) {
        float4 g = pay[p];
        float x_min = g.x, y_min = g.y, den = g.w;
        float hx, hy;
        unpack_hxy(g.z, hx, hy);
        float x_max = x_min + 2.0f * hx;
        float y_max = y_min + 2.0f * hy;
        int bxl = (int)floorf(x_min / BSX);
        int byl = (int)floorf(y_min / BSX);
        #pragma unroll
        for (int ky = 0; ky < 3; ++ky) {
            int iy = byl + ky;
            float by_lo = (float)iy * BSX;
            float oy = fminf(y_max, by_lo + BSX) - fmaxf(y_min, by_lo);
            int L = iy - row0;
            if (iy < 0 || iy >= NBY || L < 0 || L >= LROWS || !(oy > 0.0f)) continue;
            #pragma unroll
            for (int kx = 0; kx < 3; ++kx) {
                int ix = bxl + kx;
                float bx_lo = (float)ix * BSX;
                float ox = fminf(x_max, bx_lo + BSX) - fmaxf(x_min, bx_lo);
                if (ix >= 0 && ix < NBX && ox > 0.0f)
                    lds_add(&lacc[L * NBX + ix], ox * oy * den);
            }
        }
    }
    __syncthreads();
    float* dst = partial + (size_t)blockIdx.x * SCELLS;
    for (int j = tid; j < SCELLS; j += SCAT_THREADS) dst[j] = lacc[j];
}

// K5: gather replicas + y-halo, scale, clip; transpose via LDS so both the
// partial reads (contiguous x) and out writes ([x][y] layout) are coalesced
__global__ __launch_bounds__(1024) void final_kernel(
        const float* __restrict__ partial, float* __restrict__ out) {
    __shared__ float tile[32][33];
    int tx = threadIdx.x, ty = threadIdx.y;
    int x0 = blockIdx.x * 32, y0 = blockIdx.y * 32;
    int x = x0 + tx;          // x-bin (contiguous over lanes)
    int gy = y0 + ty;         // y-bin
    int s = gy >> 3, L = gy & 7;
    float sum = 0.0f;
    #pragma unroll
    for (int r = 0; r < RREP; ++r)
        sum += partial[(size_t)(s * RREP + r) * SCELLS + L * NBX + x];
    if (L < 2 && s > 0) {
        #pragma unroll
        for (int r = 0; r < RREP; ++r)
            sum += partial[(size_t)((s - 1) * RREP + r) * SCELLS + (L + SROWS) * NBX + x];
    }
    float u = sum / NORM_DIV;
    tile[ty][tx] = fminf(fmaxf(u, MIN_RATE), MAX_RATE);
    __syncthreads();
    // out[(x0+ty)*NBY + (y0+tx)] = tile[tx][ty]
    out[(x0 + ty) * NBY + (y0 + tx)] = tile[tx][ty];
}

// ---------------- fallback path (proven) ----------------

__global__ void zero_acc_kernel(float* __restrict__ acc, int n) {
    int i = blockIdx.x * blockDim.x + threadIdx.x;
    if (i < n) acc[i] = 0.0f;
}

__global__ __launch_bounds__(256) void pin_scatter_kernel(
        const float* __restrict__ pos, const float* __restrict__ nsx,
        const float* __restrict__ nsy, const float* __restrict__ pw,
        float* __restrict__ acc) {
    int i = blockIdx.x * blockDim.x + threadIdx.x;
    if (i >= NUM_PHYSICAL) return;
    float x_min, y_min, hx, hy;
    node_box(pos, nsx, nsy, i, x_min, y_min, hx, hy);
    float x_max = x_min + 2.0f * hx, y_max = y_min + 2.0f * hy;
    float density = pw[i] / (4.0f * hx * hy);
    int bxl = (int)floorf(x_min / BSX);
    int byl = (int)floorf(y_min / BSX);
    #pragma unroll
    for (int kx = 0; kx < 3; ++kx) {
        int ix = bxl + kx;
        float bx_lo = (float)ix * BSX;
        float ox = fminf(x_max, bx_lo + BSX) - fmaxf(x_min, bx_lo);
        if (ix < 0 || ix >= NBX || !(ox > 0.0f)) continue;
        #pragma unroll
        for (int ky = 0; ky < 3; ++ky) {
            int iy = byl + ky;
            float by_lo = (float)iy * BSX;
            float oy = fminf(y_max, by_lo + BSX) - fmaxf(y_min, by_lo);
            if (iy >= 0 && iy < NBY && oy > 0.0f)
                atomicAdd(&acc[ix * NBY + iy], ox * oy * density);
        }
    }
}

__global__ void finalize_kernel(float* __restrict__ out, int n) {
    int i = blockIdx.x * blockDim.x + threadIdx.x;
    if (i < n) {
        float u = out[i] / NORM_DIV;
        out[i] = fminf(fmaxf(u, MIN_RATE), MAX_RATE);
    }
}

extern "C" void kernel_launch(void* const* d_in, const int* in_sizes, int n_in,
                              void* d_out, int out_size, void* d_ws, size_t ws_size,
                              hipStream_t stream) {
    const float* pos = (const float*)d_in[0];
    const float* nsx = (const float*)d_in[1];
    const float* nsy = (const float*)d_in[2];
    const float* pw  = (const float*)d_in[3];
    float* out = (float*)d_out;

    // workspace layout (bytes)
    const size_t OFF_PAY  = 0;                                   // 2M float4 = 32,000,000
    const size_t OFF_HIST = 32000000;                            // HB*NSTRIP int = 262,144
    const size_t OFF_OFFP = OFF_HIST + (size_t)HB * NSTRIP * 4;  // 262,144
    const size_t OFF_TTOT = OFF_OFFP + (size_t)HB * NSTRIP * 4;  // 256
    const size_t OFF_TSTR = OFF_TTOT + NSTRIP * 4;               // 260
    const size_t OFF_PART = (OFF_TSTR + (NSTRIP + 1) * 4 + 255) & ~(size_t)255;
    const size_t WS_NEEDED = OFF_PART + (size_t)SCAT_BLOCKS * SCELLS * 4; // ~43.0 MB

    if (ws_size >= WS_NEEDED) {
        char* w = (char*)d_ws;
        float4* pay      = (float4*)(w + OFF_PAY);
        int*    hist_prt = (int*)   (w + OFF_HIST);
        int*    off_part = (int*)   (w + OFF_OFFP);
        int*    strip_tt = (int*)   (w + OFF_TTOT);
        int*    strip_st = (int*)   (w + OFF_TSTR);
        float*  partial  = (float*) (w + OFF_PART);

        hist_kernel<<<HB, 256, 0, stream>>>(pos, nsy, hist_prt);
        scan_blocks_kernel<<<NSTRIP, HB, 0, stream>>>(hist_prt, off_part, strip_tt);
        scan_strips_kernel<<<1, NSTRIP, 0, stream>>>(strip_tt, strip_st);
        place_kernel<<<HB, 256, 0, stream>>>(pos, nsx, nsy, pw,
                                             off_part, strip_st, pay);
        strip_scatter_kernel<<<SCAT_BLOCKS, SCAT_THREADS, 0, stream>>>(pay, strip_st, partial);
        final_kernel<<<dim3(NBX / 32, NBY / 32), dim3(32, 32), 0, stream>>>(partial, out);
    } else {
        zero_acc_kernel<<<(NBINS + 255) / 256, 256, 0, stream>>>(out, NBINS);
        pin_scatter_kernel<<<(NUM_PHYSICAL + 255) / 256, 256, 0, stream>>>(
            pos, nsx, nsy, pw, out);
        finalize_kernel<<<(NBINS + 255) / 256, 256, 0, stream>>>(out, NBINS);
    }
}

// Round 7
// 97.871 us; speedup vs baseline: 5.9825x; 1.0060x over previous
//
#include <hip/hip_runtime.h>
#include <hip/hip_fp16.h>

// Problem constants (must match reference)
#define NUM_PHYSICAL 2000000
#define NUM_NODES    2500000   // 2,000,000 physical + 500,000 filler
#define NBX 512
#define NBY 512
#define NBINS (NBX * NBY)

// BSX = BSY = 1000/512 = 1.953125 (exact in binary)
#define BSX 1.953125f
#define HALF_STRETCH ((float)(0.5 * 1.953125 * 1.4142135623730951))
// BSX*BSY*UNIT_PIN_CAPACITY = 61.03515625 (exact)
#define NORM_DIV 61.03515625f
#define MAX_RATE 2.5f
#define MIN_RATE 0.4f   // 1/2.5 exactly

// Strip bucketing: 64 strips of 8 y-rows each.
#define NSTRIP 64
#define SROWS 8                  // rows per strip
#define LROWS (SROWS + 2)        // +2 y-halo (node spans <=3 rows)
#define SCELLS (LROWS * NBX)     // 5120 floats = 20 KB LDS
#define RREP 8                   // scatter replicas per strip
#define SCAT_BLOCKS (NSTRIP * RREP)
#define SCAT_THREADS 1024        // 16 waves/block -> 2 blocks/CU = 32 waves/CU
#define HB 1024                  // blocks for hist/placement
#define CHUNK ((NUM_PHYSICAL + HB - 1) / HB)   // 1954

__device__ __forceinline__ int strip_of(float y_min) {
    int byl = (int)floorf(y_min / BSX);
    return (min(max(byl, 0), NBY - 1)) >> 3;
}

__device__ __forceinline__ void node_box(const float* __restrict__ pos,
                                         const float* __restrict__ nsx,
                                         const float* __restrict__ nsy, int i,
                                         float& x_min, float& y_min,
                                         float& hx, float& hy) {
    float sx = nsx[i], sy = nsy[i];
    hx = 0.5f * fmaxf(sx, 2.0f * HALF_STRETCH);
    hy = 0.5f * fmaxf(sy, 2.0f * HALF_STRETCH);
    x_min = (pos[i]             + 0.5f * sx) - hx;
    y_min = (pos[NUM_NODES + i] + 0.5f * sy) - hy;
}

__device__ __forceinline__ float pack_hxy(float hx, float hy) {
    unsigned int u = ((unsigned int)__half_as_ushort(__float2half_rn(hy)) << 16)
                   |  (unsigned int)__half_as_ushort(__float2half_rn(hx));
    return __uint_as_float(u);
}
__device__ __forceinline__ void unpack_hxy(float p, float& hx, float& hy) {
    unsigned int u = __float_as_uint(p);
    hx = __half2float(__ushort_as_half((unsigned short)(u & 0xffffu)));
    hy = __half2float(__ushort_as_half((unsigned short)(u >> 16)));
}

// ---------------- sorted-strip path ----------------

// K1: per-block strip histogram (y data only)
__global__ __launch_bounds__(256) void hist_kernel(
        const float* __restrict__ pos, const float* __restrict__ nsy,
        int* __restrict__ hist_part) {
    __shared__ int lh[NSTRIP];
    int tid = threadIdx.x, b = blockIdx.x;
    if (tid < NSTRIP) lh[tid] = 0;
    __syncthreads();
    int lo = b * CHUNK, hi = min(lo + CHUNK, NUM_PHYSICAL);
    for (int i = lo + tid; i < hi; i += 256) {
        float sy = nsy[i];
        float hy = 0.5f * fmaxf(sy, 2.0f * HALF_STRETCH);
        float y_min = (pos[NUM_NODES + i] + 0.5f * sy) - hy;
        atomicAdd(&lh[strip_of(y_min)], 1);
    }
    __syncthreads();
    if (tid < NSTRIP) hist_part[b * NSTRIP + tid] = lh[tid];
}

// K2a: per strip, exclusive prefix over the HB blocks' counts
__global__ __launch_bounds__(1024) void scan_blocks_kernel(
        const int* __restrict__ hist_part, int* __restrict__ off_part,
        int* __restrict__ strip_total) {
    __shared__ int sc[2][HB];
    int s = blockIdx.x, b = threadIdx.x;
    int v = hist_part[b * NSTRIP + s];
    sc[0][b] = v;
    int src = 0;
    for (int off = 1; off < HB; off <<= 1) {
        __syncthreads();
        int x = sc[src][b];
        if (b >= off) x += sc[src][b - off];
        sc[src ^ 1][b] = x;
        src ^= 1;
    }
    __syncthreads();
    int incl = sc[src][b];
    off_part[b * NSTRIP + s] = incl - v;   // exclusive prefix
    if (b == HB - 1) strip_total[s] = incl;
}

// K2b: exclusive prefix over the 64 strip totals
__global__ __launch_bounds__(64) void scan_strips_kernel(
        const int* __restrict__ strip_total, int* __restrict__ strip_start) {
    __shared__ int sc[2][NSTRIP];
    int t = threadIdx.x;
    int v = strip_total[t];
    sc[0][t] = v;
    int src = 0;
    for (int off = 1; off < NSTRIP; off <<= 1) {
        __syncthreads();
        int x = sc[src][t];
        if (t >= off) x += sc[src][t - off];
        sc[src ^ 1][t] = x;
        src ^= 1;
    }
    __syncthreads();
    int incl = sc[src][t];
    strip_start[t] = incl - v;
    if (t == NSTRIP - 1) strip_start[NSTRIP] = incl;
}

// K3: place compressed 16B payloads at sorted positions (deterministic slots,
// no global atomics — per-block cursors are exact from the scans)
__global__ __launch_bounds__(256) void place_kernel(
        const float* __restrict__ pos, const float* __restrict__ nsx,
        const float* __restrict__ nsy, const float* __restrict__ pw,
        const int* __restrict__ off_part, const int* __restrict__ strip_start,
        float4* __restrict__ pay) {
    __shared__ int lcur[NSTRIP];
    int tid = threadIdx.x, b = blockIdx.x;
    if (tid < NSTRIP) lcur[tid] = strip_start[tid] + off_part[b * NSTRIP + tid];
    __syncthreads();
    int lo = b * CHUNK, hi = min(lo + CHUNK, NUM_PHYSICAL);
    for (int i = lo + tid; i < hi; i += 256) {
        float x_min, y_min, hx, hy;
        node_box(pos, nsx, nsy, i, x_min, y_min, hx, hy);
        float density = pw[i] / (4.0f * hx * hy);
        int s = strip_of(y_min);
        int p = atomicAdd(&lcur[s], 1);
        pay[p] = make_float4(x_min, y_min, pack_hxy(hx, hy), density);
    }
}

// K4: strip scatter — LDS accumulate (8+2 rows x 512 cols), plain stores.
// LDS atomics issued as raw ds_add_f32 (fire-and-forget, no per-op wait);
// a single lgkmcnt(0) drain precedes the final barrier.
__global__ __launch_bounds__(SCAT_THREADS) void strip_scatter_kernel(
        const float4* __restrict__ pay, const int* __restrict__ strip_start,
        float* __restrict__ partial) {
    __shared__ float lacc[SCELLS];
    int tid = threadIdx.x;
    int s = blockIdx.x >> 3, r = blockIdx.x & (RREP - 1);
    for (int j = tid; j < SCELLS; j += SCAT_THREADS) lacc[j] = 0.0f;
    __syncthreads();
    // LDS byte offset of lacc[0] (low 32 bits of the generic pointer are the
    // LDS window offset on gfx9+)
    unsigned int lds_base = (unsigned int)(uintptr_t)&lacc[0];
    int lo0 = strip_start[s], count = strip_start[s + 1] - lo0;
    int lo = lo0 + (int)(((long long)count * r) / RREP);
    int hi = lo0 + (int)(((long long)count * (r + 1)) / RREP);
    int row0 = s * SROWS;
    for (int p = lo + tid; p < hi; p += SCAT_THREADS) {
        float4 g = pay[p];
        float x_min = g.x, y_min = g.y, den = g.w;
        float hx, hy;
        unpack_hxy(g.z, hx, hy);
        float x_max = x_min + 2.0f * hx;
        float y_max = y_min + 2.0f * hy;
        int bxl = (int)floorf(x_min / BSX);
        int byl = (int)floorf(y_min / BSX);
        #pragma unroll
        for (int ky = 0; ky < 3; ++ky) {
            int iy = byl + ky;
            float by_lo = (float)iy * BSX;
            float oy = fminf(y_max, by_lo + BSX) - fmaxf(y_min, by_lo);
            int L = iy - row0;
            if (iy < 0 || iy >= NBY || L < 0 || L >= LROWS || !(oy > 0.0f)) continue;
            float wrow = oy * den;
            unsigned int row_base = lds_base + 4u * (unsigned int)(L * NBX);
            #pragma unroll
            for (int kx = 0; kx < 3; ++kx) {
                int ix = bxl + kx;
                float bx_lo = (float)ix * BSX;
                float ox = fminf(x_max, bx_lo + BSX) - fmaxf(x_min, bx_lo);
                if (ix >= 0 && ix < NBX && ox > 0.0f) {
                    unsigned int off = row_base + 4u * (unsigned int)ix;
                    float v = ox * wrow;
                    asm volatile("ds_add_f32 %0, %1" :: "v"(off), "v"(v));
                }
            }
        }
    }
    // drain all outstanding ds_add ops, then make them visible to the block
    asm volatile("s_waitcnt lgkmcnt(0)" ::: "memory");
    __syncthreads();
    float* dst = partial + (size_t)blockIdx.x * SCELLS;
    for (int j = tid; j < SCELLS; j += SCAT_THREADS) dst[j] = lacc[j];
}

// K5: gather replicas + y-halo, scale, clip; transpose via LDS so both the
// partial reads (contiguous x) and out writes ([x][y] layout) are coalesced
__global__ __launch_bounds__(1024) void final_kernel(
        const float* __restrict__ partial, float* __restrict__ out) {
    __shared__ float tile[32][33];
    int tx = threadIdx.x, ty = threadIdx.y;
    int x0 = blockIdx.x * 32, y0 = blockIdx.y * 32;
    int x = x0 + tx;          // x-bin (contiguous over lanes)
    int gy = y0 + ty;         // y-bin
    int s = gy >> 3, L = gy & 7;
    float sum = 0.0f;
    #pragma unroll
    for (int r = 0; r < RREP; ++r)
        sum += partial[(size_t)(s * RREP + r) * SCELLS + L * NBX + x];
    if (L < 2 && s > 0) {
        #pragma unroll
        for (int r = 0; r < RREP; ++r)
            sum += partial[(size_t)((s - 1) * RREP + r) * SCELLS + (L + SROWS) * NBX + x];
    }
    float u = sum / NORM_DIV;
    tile[ty][tx] = fminf(fmaxf(u, MIN_RATE), MAX_RATE);
    __syncthreads();
    // out[(x0+ty)*NBY + (y0+tx)] = tile[tx][ty]
    out[(x0 + ty) * NBY + (y0 + tx)] = tile[tx][ty];
}

// ---------------- fallback path (proven) ----------------

__global__ void zero_acc_kernel(float* __restrict__ acc, int n) {
    int i = blockIdx.x * blockDim.x + threadIdx.x;
    if (i < n) acc[i] = 0.0f;
}

__global__ __launch_bounds__(256) void pin_scatter_kernel(
        const float* __restrict__ pos, const float* __restrict__ nsx,
        const float* __restrict__ nsy, const float* __restrict__ pw,
        float* __restrict__ acc) {
    int i = blockIdx.x * blockDim.x + threadIdx.x;
    if (i >= NUM_PHYSICAL) return;
    float x_min, y_min, hx, hy;
    node_box(pos, nsx, nsy, i, x_min, y_min, hx, hy);
    float x_max = x_min + 2.0f * hx, y_max = y_min + 2.0f * hy;
    float density = pw[i] / (4.0f * hx * hy);
    int bxl = (int)floorf(x_min / BSX);
    int byl = (int)floorf(y_min / BSX);
    #pragma unroll
    for (int kx = 0; kx < 3; ++kx) {
        int ix = bxl + kx;
        float bx_lo = (float)ix * BSX;
        float ox = fminf(x_max, bx_lo + BSX) - fmaxf(x_min, bx_lo);
        if (ix < 0 || ix >= NBX || !(ox > 0.0f)) continue;
        #pragma unroll
        for (int ky = 0; ky < 3; ++ky) {
            int iy = byl + ky;
            float by_lo = (float)iy * BSX;
            float oy = fminf(y_max, by_lo + BSX) - fmaxf(y_min, by_lo);
            if (iy >= 0 && iy < NBY && oy > 0.0f)
                atomicAdd(&acc[ix * NBY + iy], ox * oy * density);
        }
    }
}

__global__ void finalize_kernel(float* __restrict__ out, int n) {
    int i = blockIdx.x * blockDim.x + threadIdx.x;
    if (i < n) {
        float u = out[i] / NORM_DIV;
        out[i] = fminf(fmaxf(u, MIN_RATE), MAX_RATE);
    }
}

extern "C" void kernel_launch(void* const* d_in, const int* in_sizes, int n_in,
                              void* d_out, int out_size, void* d_ws, size_t ws_size,
                              hipStream_t stream) {
    const float* pos = (const float*)d_in[0];
    const float* nsx = (const float*)d_in[1];
    const float* nsy = (const float*)d_in[2];
    const float* pw  = (const float*)d_in[3];
    float* out = (float*)d_out;

    // workspace layout (bytes)
    const size_t OFF_PAY  = 0;                                   // 2M float4 = 32,000,000
    const size_t OFF_HIST = 32000000;                            // HB*NSTRIP int = 262,144
    const size_t OFF_OFFP = OFF_HIST + (size_t)HB * NSTRIP * 4;  // 262,144
    const size_t OFF_TTOT = OFF_OFFP + (size_t)HB * NSTRIP * 4;  // 256
    const size_t OFF_TSTR = OFF_TTOT + NSTRIP * 4;               // 260
    const size_t OFF_PART = (OFF_TSTR + (NSTRIP + 1) * 4 + 255) & ~(size_t)255;
    const size_t WS_NEEDED = OFF_PART + (size_t)SCAT_BLOCKS * SCELLS * 4; // ~43.0 MB

    if (ws_size >= WS_NEEDED) {
        char* w = (char*)d_ws;
        float4* pay      = (float4*)(w + OFF_PAY);
        int*    hist_prt = (int*)   (w + OFF_HIST);
        int*    off_part = (int*)   (w + OFF_OFFP);
        int*    strip_tt = (int*)   (w + OFF_TTOT);
        int*    strip_st = (int*)   (w + OFF_TSTR);
        float*  partial  = (float*) (w + OFF_PART);

        hist_kernel<<<HB, 256, 0, stream>>>(pos, nsy, hist_prt);
        scan_blocks_kernel<<<NSTRIP, HB, 0, stream>>>(hist_prt, off_part, strip_tt);
        scan_strips_kernel<<<1, NSTRIP, 0, stream>>>(strip_tt, strip_st);
        place_kernel<<<HB, 256, 0, stream>>>(pos, nsx, nsy, pw,
                                             off_part, strip_st, pay);
        strip_scatter_kernel<<<SCAT_BLOCKS, SCAT_THREADS, 0, stream>>>(pay, strip_st, partial);
        final_kernel<<<dim3(NBX / 32, NBY / 32), dim3(32, 32), 0, stream>>>(partial, out);
    } else {
        zero_acc_kernel<<<(NBINS + 255) / 256, 256, 0, stream>>>(out, NBINS);
        pin_scatter_kernel<<<(NUM_PHYSICAL + 255) / 256, 256, 0, stream>>>(
            pos, nsx, nsy, pw, out);
        finalize_kernel<<<(NBINS + 255) / 256, 256, 0, stream>>>(out, NBINS);
    }
}